// Round 6
// baseline (330.064 us; speedup 1.0000x reference)
//
#include <hip/hip_runtime.h>

// Adaptive_Node_Scale_GCN — MFMA v5 (v4 + TA-coalescing rebuild).
// Y[d,n] = sum_{t=0..6} W_t,d · X_{d,n} · M_{t,d}^T,  M ∈ {I, A0, A0², A1, A1², P_d, P_d²}
// v5 changes vs v4 (all memory-path, math identical):
//  - out writes bounce through LDS (32KB Y chunk overlaying dead Z region) and are
//    issued as dwordx4 with lanes spanning k: 8x fewer L2 line transactions.
//  - X global loads re-laned: 32 lines/instr @32B used (was 64 lines @16B).
//  - __launch_bounds__(256,4): 4 blocks/CU (1024 blocks = exactly 4/CU).

namespace {

constexpr int Kn = 128;
constexpr int En = 10;

typedef __attribute__((ext_vector_type(8))) short short8;
typedef __attribute__((ext_vector_type(4))) float f32x4;

__device__ inline unsigned short f2bf(float f) {
    unsigned x = __float_as_uint(f);
    return (unsigned short)((x + 0x7FFFu + ((x >> 16) & 1u)) >> 16);
}
__device__ inline unsigned pack2(float lo, float hi) {
    return (unsigned)f2bf(lo) | ((unsigned)f2bf(hi) << 16);
}

// ---------------- precompute 1: fp32 mats ----------------
// fp32 slots: 0:A0 2:A1 4..7:P_d
__global__ __launch_bounds__(256) void build_adj(
    const float* __restrict__ supports,
    const float* __restrict__ nv1,
    const float* __restrict__ nv2,
    const float* __restrict__ impW,
    const float* __restrict__ impB,
    float* __restrict__ mats)
{
    const int tid = threadIdx.x;
    const int blk = blockIdx.x;
    if (blk < 2) {
        const float* A = supports + blk * Kn * Kn;
        float* dst = mats + (blk * 2) * Kn * Kn;   // slot 0 / slot 2
        for (int i = tid; i < Kn * Kn; i += 256) dst[i] = A[i];
        return;
    }
    const int d = blk - 2;
    __shared__ float nv1m[Kn * En];
    __shared__ float nv2s[En * Kn];
    for (int i = tid; i < Kn * En; i += 256) nv1m[i] = nv1[d * Kn * En + i];
    for (int i = tid; i < En * Kn; i += 256) nv2s[i] = nv2[d * En * Kn + i];
    __syncthreads();
    float impv[5];
    #pragma unroll
    for (int r = 0; r < 5; ++r) {
        const int idx = tid + r * 256;
        const int j = idx / En, e = idx - j * En;
        float acc = impB[j];
        for (int kk = 0; kk < Kn; ++kk)
            acc += impW[j * Kn + kk] * nv1m[kk * En + e];
        impv[r] = acc;
    }
    __syncthreads();
    #pragma unroll
    for (int r = 0; r < 5; ++r) nv1m[tid + r * 256] *= impv[r];
    __syncthreads();
    if (tid < Kn) {
        const int k = tid;
        float a[En];
        #pragma unroll
        for (int e = 0; e < En; ++e) a[e] = nv1m[k * En + e];
        float mx = 0.f;
        for (int j = 0; j < Kn; ++j) {
            float s = 0.f;
            #pragma unroll
            for (int e = 0; e < En; ++e) s += a[e] * nv2s[e * Kn + j];
            mx = fmaxf(mx, s);
        }
        float sum = 0.f;
        for (int j = 0; j < Kn; ++j) {
            float s = 0.f;
            #pragma unroll
            for (int e = 0; e < En; ++e) s += a[e] * nv2s[e * Kn + j];
            s = fmaxf(s, 0.f);
            sum += expf(s - mx);
        }
        const float inv = 1.f / sum;
        float* dst = mats + (4 + d) * Kn * Kn;
        for (int j = 0; j < Kn; ++j) {
            float s = 0.f;
            #pragma unroll
            for (int e = 0; e < En; ++e) s += a[e] * nv2s[e * Kn + j];
            s = fmaxf(s, 0.f);
            dst[k * Kn + j] = expf(s - mx) * inv;   // P[k][j], row-major
        }
    }
}

// ---------------- precompute 2: squares + bf16 stream (merged) ----------------
// wbm slots (plain row-major M[k][v] bf16):
//   0:I 1:A0 2:A0² 3:A1 4:A1² 5+2d:P_d 6+2d:P²_d
__global__ __launch_bounds__(256) void square_cvt(
    const float* __restrict__ fm, unsigned short* __restrict__ wbm)
{
    const int tid = threadIdx.x;
    if (blockIdx.x < 96) {
        __shared__ float S[Kn * Kn];
        const int m = blockIdx.x >> 4, strip = blockIdx.x & 15;
        const int src = (m == 0) ? 0 : (m == 1) ? 2 : (2 + m);     // fp32 slot
        const int dst = (m == 0) ? 2 : (m == 1) ? 4 : (2 + 2 * m); // wbm slot
        const float* s = fm + src * Kn * Kn;
        unsigned short* o = wbm + dst * Kn * Kn;
        for (int i = tid; i < Kn * Kn; i += 256) S[i] = s[i];
        __syncthreads();
        const int v = strip * 8 + (tid >> 5);
        const int k0 = (tid & 31) * 4;
        float acc0 = 0.f, acc1 = 0.f, acc2 = 0.f, acc3 = 0.f;
        for (int u0 = 0; u0 < Kn; u0 += 4) {
            const float4 av = *reinterpret_cast<const float4*>(&S[v * Kn + u0]);
            const float a[4] = {av.x, av.y, av.z, av.w};
            #pragma unroll
            for (int j = 0; j < 4; ++j) {
                const float4 m4 = *reinterpret_cast<const float4*>(&S[(u0 + j) * Kn + k0]);
                acc0 += a[j] * m4.x; acc1 += a[j] * m4.y;
                acc2 += a[j] * m4.z; acc3 += a[j] * m4.w;
            }
        }
        uint2 r;
        r.x = pack2(acc0, acc1);
        r.y = pack2(acc2, acc3);
        *reinterpret_cast<uint2*>(&o[v * Kn + k0]) = r;
    } else {
        const int s = blockIdx.x - 96;  // 0..6
        const int wslot = (s == 0) ? 0 : (s == 1) ? 1 : (s == 2) ? 3 : (5 + 2 * (s - 3));
        const int fsrc  = (s == 0) ? -1 : (s == 1) ? 0 : (s == 2) ? 2 : (4 + (s - 3));
        for (int i = tid; i < Kn * Kn; i += 256) {
            const int k = i >> 7, v = i & 127;
            const float val = (fsrc < 0) ? ((k == v) ? 1.f : 0.f) : fm[fsrc * 16384 + i];
            wbm[wslot * 16384 + i] = f2bf(val);
        }
    }
}

// ---------------- fused MFMA kernel ----------------
// block = (d, b, 8 l's); kh looped. LDS 32KB, triple-overlaid:
//   X-stage rows (n*16+c)×256B  ->  Z [n][kp64][tp2][c16] bf16  ->  Y [o][k64][l8] f32
__global__ __launch_bounds__(256, 4) void fused_mfma(
    const float* __restrict__ x,
    const unsigned short* __restrict__ wbm,
    const float* __restrict__ mlpW,   // (4,16,112)
    const float* __restrict__ mlpB,   // (4,16)
    float* __restrict__ out)
{
    __shared__ __align__(16) char lds[32768];
    const int tid = threadIdx.x;
    const int lane = tid & 63, lr = lane & 15, lg = lane >> 4;
    const int wid = tid >> 6, wr = wid >> 1, wk = wid & 1;

    const unsigned u = blockIdx.x;                 // 0..1023
    const unsigned pid = (u & 7) * 128 + (u >> 3); // XCD-chunked
    const int lt = pid & 15;
    const int b  = (pid >> 4) & 15;
    const int d  = (int)(pid >> 8);
    const int l0 = lt * 8;

    // ---- stage X: lanes = (v-pair, l-half) -> 32 lines/instr @32B used.
    // LDS row (n*16+c)*256B, col byte = 4*p ^ ((c&7)<<4)   (p = v/2)
    {
        const int half = tid & 1;            // l-half (4 floats)
        const int p5 = (tid >> 1) & 31;      // v-pair low bits
        #pragma unroll
        for (int i = 0; i < 8; ++i) {
            const int g = i * 4 + wid;       // 0..31
            const int c = g >> 1, pg = g & 1;
            const int p = pg * 32 + p5;      // v-pair 0..63
            const int v = p * 2;
            const float* p0 = x + (size_t)b * 1048576 + c * 65536 + d * 16384 +
                              v * 128 + l0 + half * 4;
            const float4 q0 = *reinterpret_cast<const float4*>(p0);        // v
            const float4 q1 = *reinterpret_cast<const float4*>(p0 + 128);  // v+1
            const float a0[4] = {q0.x, q0.y, q0.z, q0.w};
            const float a1[4] = {q1.x, q1.y, q1.z, q1.w};
            const int colb = (4 * p) ^ ((c & 7) << 4);
            #pragma unroll
            for (int j = 0; j < 4; ++j) {
                const int n = half * 4 + j;
                *reinterpret_cast<unsigned*>(lds + (n * 16 + c) * 256 + colb) =
                    pack2(a0[j], a1[j]);
            }
        }
    }

    // ---- W fragments (A-operand of phase B), zero-padded 8th t-slot
    short8 Wf[4];
    #pragma unroll
    for (int p = 0; p < 4; ++p) {
        short8 w;
        #pragma unroll
        for (int j = 0; j < 8; ++j) {
            const int tc = lg * 8 + j, t = 2 * p + (tc >> 4), c = tc & 15;
            const float wv = (t < 7) ? mlpW[d * 1792 + lr * 112 + t * 16 + c] : 0.f;
            w[j] = (short)f2bf(wv);
        }
        Wf[p] = w;
    }

    __syncthreads();   // X staged

    // ---- X A-fragments -> registers (valid for both kh; X LDS dead after)
    short8 Xf[4][4];
    {
        const int swz = (lr & 7) << 4;
        #pragma unroll
        for (int rti = 0; rti < 4; ++rti) {
            const int base = ((wr * 4 + rti) * 16 + lr) * 256;
            #pragma unroll
            for (int ks = 0; ks < 4; ++ks)
                Xf[rti][ks] = *reinterpret_cast<const short8*>(
                    lds + base + ((ks * 64 + lg * 16) ^ swz));
        }
    }
    __syncthreads();   // all waves done reading X before Z overlay writes

    const f32x4 zero4 = {0.f, 0.f, 0.f, 0.f};

    #pragma unroll 1
    for (int kh2 = 0; kh2 < 2; ++kh2) {
        f32x4 Y[2][4];
        #pragma unroll
        for (int ni = 0; ni < 2; ++ni)
            #pragma unroll
            for (int kt = 0; kt < 4; ++kt) Y[ni][kt] = zero4;

        #pragma unroll
        for (int p = 0; p < 4; ++p) {
            #pragma unroll
            for (int tp = 0; tp < ((p < 3) ? 2 : 1); ++tp) {
                const int tpos = 2 * p + tp;
                const int slot = (tpos < 5) ? tpos : (5 + 2 * d + (tpos - 5));
                const unsigned short* mb =
                    wbm + slot * 16384 + kh2 * 8192 + wk * 4096 + lr * 128 + lg * 8;
                f32x4 D[4][2];
                #pragma unroll
                for (int rti = 0; rti < 4; ++rti) {
                    D[rti][0] = zero4; D[rti][1] = zero4;
                }
                #pragma unroll
                for (int ks = 0; ks < 4; ++ks) {
                    const short8 Bf0 = *reinterpret_cast<const short8*>(mb + ks * 32);
                    const short8 Bf1 = *reinterpret_cast<const short8*>(mb + 2048 + ks * 32);
                    #pragma unroll
                    for (int rti = 0; rti < 4; ++rti) {
                        D[rti][0] = __builtin_amdgcn_mfma_f32_16x16x32_bf16(
                            Xf[rti][ks], Bf0, D[rti][0], 0, 0, 0);
                        D[rti][1] = __builtin_amdgcn_mfma_f32_16x16x32_bf16(
                            Xf[rti][ks], Bf1, D[rti][1], 0, 0, 0);
                    }
                }
                // write Z[n][kp][tp][c] bf16
                #pragma unroll
                for (int rti = 0; rti < 4; ++rti) {
                    #pragma unroll
                    for (int j = 0; j < 2; ++j) {
                        const int n = wr * 4 + rti;
                        const int kp = (wk * 2 + j) * 16 + lr;
                        uint2 zz;
                        zz.x = pack2(D[rti][j][0], D[rti][j][1]);
                        zz.y = pack2(D[rti][j][2], D[rti][j][3]);
                        *reinterpret_cast<uint2*>(
                            lds + n * 4096 +
                            ((kp * 64 + tp * 32 + lg * 8) ^ ((kp & 7) << 4))) = zz;
                        if (tpos == 6) {
                            const uint2 z0 = {0u, 0u};
                            *reinterpret_cast<uint2*>(
                                lds + n * 4096 +
                                ((kp * 64 + 32 + lg * 8) ^ ((kp & 7) << 4))) = z0;
                        }
                    }
                }
            }
            __syncthreads();   // Z(pair) visible

            // phase B: Y += W_pair · Z
            #pragma unroll
            for (int ni = 0; ni < 2; ++ni) {
                const int n = wid * 2 + ni;
                #pragma unroll
                for (int ktl = 0; ktl < 4; ++ktl) {
                    const int kp = ktl * 16 + lr;
                    const short8 Bfz = *reinterpret_cast<const short8*>(
                        lds + n * 4096 + ((kp * 64 + lg * 16) ^ ((kp & 7) << 4)));
                    Y[ni][ktl] = __builtin_amdgcn_mfma_f32_16x16x32_bf16(
                        Wf[p], Bfz, Y[ni][ktl], 0, 0, 0);
                }
            }
            __syncthreads();   // Z free for next pair
        }

        // ---- Y bounce: regs -> LDS [o][k64][l8] f32 (byte ^= (k&12)), then
        //      coalesced dwordx4 global stores with lanes spanning (k, l-half).
        {
            const float2 bias2 = {mlpB[d * 16 + lg * 4],  0.f};
            #pragma unroll
            for (int ni = 0; ni < 2; ++ni) {
                const int l = wid * 2 + ni;
                #pragma unroll
                for (int ktl = 0; ktl < 4; ++ktl) {
                    const int k = ktl * 16 + lr;
                    #pragma unroll
                    for (int r = 0; r < 4; ++r) {
                        const int o = lg * 4 + r;
                        *reinterpret_cast<float*>(
                            lds + o * 2048 + k * 32 + ((l * 4) ^ (k & 12))) =
                            Y[ni][ktl][r];
                    }
                }
            }
        }
        __syncthreads();   // Y chunk complete

        {
            const int half = tid & 1;
            const int klo = (tid >> 1) & 31;
            #pragma unroll
            for (int i = 0; i < 8; ++i) {
                const int g = i * 4 + wid;        // 0..31
                const int o = g >> 1, kg = g & 1;
                const int k = kg * 32 + klo;      // 0..63 local
                const int pp = (k >> 2) & 3;
                const float4 F = *reinterpret_cast<const float4*>(
                    lds + o * 2048 + k * 32 + half * 16);
                // un-permute: out[j] = F[j ^ pp]
                float4 s1, s2;
                if (pp & 1) { s1.x = F.y; s1.y = F.x; s1.z = F.w; s1.w = F.z; }
                else        { s1 = F; }
                if (pp & 2) { s2.x = s1.z; s2.y = s1.w; s2.z = s1.x; s2.w = s1.y; }
                else        { s2 = s1; }
                const float bv = mlpB[d * 16 + o];
                s2.x += bv; s2.y += bv; s2.z += bv; s2.w += bv;
                float* gp = out + (size_t)b * 1048576 + o * 65536 + d * 16384 +
                            (kh2 * 64 + k) * 128 + l0 + half * 4;
                *reinterpret_cast<float4*>(gp) = s2;
            }
        }
        __syncthreads();   // Y region free for next kh2's Z writes
    }
}

}  // namespace

extern "C" void kernel_launch(void* const* d_in, const int* in_sizes, int n_in,
                              void* d_out, int out_size, void* d_ws, size_t ws_size,
                              hipStream_t stream)
{
    const float* x    = (const float*)d_in[0];
    const float* sup  = (const float*)d_in[1];
    const float* nv1  = (const float*)d_in[2];
    const float* nv2  = (const float*)d_in[3];
    const float* impW = (const float*)d_in[4];
    const float* impB = (const float*)d_in[5];
    const float* mlpW = (const float*)d_in[6];
    const float* mlpB = (const float*)d_in[7];
    float* outp = (float*)d_out;

    float* fm = (float*)d_ws;                                        // fp32 mats
    unsigned short* wbm = (unsigned short*)((char*)d_ws + 786432);   // 13 × 32KB bf16

    build_adj<<<6, 256, 0, stream>>>(sup, nv1, nv2, impW, impB, fm);
    square_cvt<<<103, 256, 0, stream>>>(fm, wbm);
    fused_mfma<<<1024, 256, 0, stream>>>(x, wbm, mlpW, mlpB, outp);
}

// Round 7
// 140.241 us; speedup vs baseline: 2.3536x; 2.3536x over previous
//
#include <hip/hip_runtime.h>

// Adaptive_Node_Scale_GCN — MFMA v6.
// Y[d,n] = sum_{t=0..6} W_t,d · X_{d,n} · M_{t,d}^T,  M ∈ {I, A0, A0², A1, A1², P_d, P_d²}
// v6 = v2 schedule skeleton (2048 blocks, kh in grid) + M B-frags direct from global
// with REGISTER double-buffer prefetch (no M LDS, no M barriers) + v5 TA coalescing
// (remapped X loads, Y LDS-bounce stores) + __launch_bounds__(256,2) so the ~234
// unified regs fit WITHOUT spilling (v5 failure: (256,4) -> 128-reg cap -> scratch).

namespace {

constexpr int Kn = 128;
constexpr int En = 10;

typedef __attribute__((ext_vector_type(8))) short short8;
typedef __attribute__((ext_vector_type(4))) float f32x4;

__device__ inline unsigned short f2bf(float f) {
    unsigned x = __float_as_uint(f);
    return (unsigned short)((x + 0x7FFFu + ((x >> 16) & 1u)) >> 16);
}
__device__ inline unsigned pack2(float lo, float hi) {
    return (unsigned)f2bf(lo) | ((unsigned)f2bf(hi) << 16);
}

// ---------------- precompute 1: fp32 mats ----------------
// fp32 slots: 0:A0 2:A1 4..7:P_d
__global__ __launch_bounds__(256) void build_adj(
    const float* __restrict__ supports,
    const float* __restrict__ nv1,
    const float* __restrict__ nv2,
    const float* __restrict__ impW,
    const float* __restrict__ impB,
    float* __restrict__ mats)
{
    const int tid = threadIdx.x;
    const int blk = blockIdx.x;
    if (blk < 2) {
        const float* A = supports + blk * Kn * Kn;
        float* dst = mats + (blk * 2) * Kn * Kn;   // slot 0 / slot 2
        for (int i = tid; i < Kn * Kn; i += 256) dst[i] = A[i];
        return;
    }
    const int d = blk - 2;
    __shared__ float nv1m[Kn * En];
    __shared__ float nv2s[En * Kn];
    for (int i = tid; i < Kn * En; i += 256) nv1m[i] = nv1[d * Kn * En + i];
    for (int i = tid; i < En * Kn; i += 256) nv2s[i] = nv2[d * En * Kn + i];
    __syncthreads();
    float impv[5];
    #pragma unroll
    for (int r = 0; r < 5; ++r) {
        const int idx = tid + r * 256;
        const int j = idx / En, e = idx - j * En;
        float acc = impB[j];
        for (int kk = 0; kk < Kn; ++kk)
            acc += impW[j * Kn + kk] * nv1m[kk * En + e];
        impv[r] = acc;
    }
    __syncthreads();
    #pragma unroll
    for (int r = 0; r < 5; ++r) nv1m[tid + r * 256] *= impv[r];
    __syncthreads();
    if (tid < Kn) {
        const int k = tid;
        float a[En];
        #pragma unroll
        for (int e = 0; e < En; ++e) a[e] = nv1m[k * En + e];
        float mx = 0.f;
        for (int j = 0; j < Kn; ++j) {
            float s = 0.f;
            #pragma unroll
            for (int e = 0; e < En; ++e) s += a[e] * nv2s[e * Kn + j];
            mx = fmaxf(mx, s);
        }
        float sum = 0.f;
        for (int j = 0; j < Kn; ++j) {
            float s = 0.f;
            #pragma unroll
            for (int e = 0; e < En; ++e) s += a[e] * nv2s[e * Kn + j];
            s = fmaxf(s, 0.f);
            sum += expf(s - mx);
        }
        const float inv = 1.f / sum;
        float* dst = mats + (4 + d) * Kn * Kn;
        for (int j = 0; j < Kn; ++j) {
            float s = 0.f;
            #pragma unroll
            for (int e = 0; e < En; ++e) s += a[e] * nv2s[e * Kn + j];
            s = fmaxf(s, 0.f);
            dst[k * Kn + j] = expf(s - mx) * inv;   // P[k][j], row-major
        }
    }
}

// ---------------- precompute 2: squares + bf16 stream (merged) ----------------
// wbm slots (plain row-major M[k][v] bf16):
//   0:I 1:A0 2:A0² 3:A1 4:A1² 5+2d:P_d 6+2d:P²_d
__global__ __launch_bounds__(256) void square_cvt(
    const float* __restrict__ fm, unsigned short* __restrict__ wbm)
{
    const int tid = threadIdx.x;
    if (blockIdx.x < 96) {
        __shared__ float S[Kn * Kn];
        const int m = blockIdx.x >> 4, strip = blockIdx.x & 15;
        const int src = (m == 0) ? 0 : (m == 1) ? 2 : (2 + m);     // fp32 slot
        const int dst = (m == 0) ? 2 : (m == 1) ? 4 : (2 + 2 * m); // wbm slot
        const float* s = fm + src * Kn * Kn;
        unsigned short* o = wbm + dst * Kn * Kn;
        for (int i = tid; i < Kn * Kn; i += 256) S[i] = s[i];
        __syncthreads();
        const int v = strip * 8 + (tid >> 5);
        const int k0 = (tid & 31) * 4;
        float acc0 = 0.f, acc1 = 0.f, acc2 = 0.f, acc3 = 0.f;
        for (int u0 = 0; u0 < Kn; u0 += 4) {
            const float4 av = *reinterpret_cast<const float4*>(&S[v * Kn + u0]);
            const float a[4] = {av.x, av.y, av.z, av.w};
            #pragma unroll
            for (int j = 0; j < 4; ++j) {
                const float4 m4 = *reinterpret_cast<const float4*>(&S[(u0 + j) * Kn + k0]);
                acc0 += a[j] * m4.x; acc1 += a[j] * m4.y;
                acc2 += a[j] * m4.z; acc3 += a[j] * m4.w;
            }
        }
        uint2 r;
        r.x = pack2(acc0, acc1);
        r.y = pack2(acc2, acc3);
        *reinterpret_cast<uint2*>(&o[v * Kn + k0]) = r;
    } else {
        const int s = blockIdx.x - 96;  // 0..6
        const int wslot = (s == 0) ? 0 : (s == 1) ? 1 : (s == 2) ? 3 : (5 + 2 * (s - 3));
        const int fsrc  = (s == 0) ? -1 : (s == 1) ? 0 : (s == 2) ? 2 : (4 + (s - 3));
        for (int i = tid; i < Kn * Kn; i += 256) {
            const int k = i >> 7, v = i & 127;
            const float val = (fsrc < 0) ? ((k == v) ? 1.f : 0.f) : fm[fsrc * 16384 + i];
            wbm[wslot * 16384 + i] = f2bf(val);
        }
    }
}

// ---------------- fused MFMA kernel ----------------
// block = (d, b, 8 l's, kh). LDS 32KB triple-overlaid:
//   X-stage rows (n*16+c)×256B -> Z [n][kp64][tp2][c16] bf16 -> Y [o][k64][l8] f32
__global__ __launch_bounds__(256, 2) void fused_mfma(
    const float* __restrict__ x,
    const unsigned short* __restrict__ wbm,
    const float* __restrict__ mlpW,   // (4,16,112)
    const float* __restrict__ mlpB,   // (4,16)
    float* __restrict__ out)
{
    __shared__ __align__(16) char lds[32768];
    const int tid = threadIdx.x;
    const int lane = tid & 63, lr = lane & 15, lg = lane >> 4;
    const int wid = tid >> 6, wr = wid >> 1, wk = wid & 1;

    const unsigned u = blockIdx.x;                 // 0..2047
    const unsigned pid = (u & 7) * 256 + (u >> 3); // XCD-chunked; kh/lt siblings same XCD
    const int kh = pid & 1;
    const int lt = (pid >> 1) & 15;
    const int b  = (pid >> 5) & 15;
    const int d  = (int)(pid >> 9);
    const int l0 = lt * 8;

    const f32x4 zero4 = {0.f, 0.f, 0.f, 0.f};
    short8 Mb0[8], Mb1[8];
    const unsigned short* mbase = wbm + kh * 8192 + wk * 4096 + lr * 128 + lg * 8;

    auto loadM = [&](int slot, short8 (&dst)[8]) {
        const unsigned short* mp = mbase + slot * 16384;
        #pragma unroll
        for (int j = 0; j < 2; ++j)
            #pragma unroll
            for (int ks = 0; ks < 4; ++ks)
                dst[j * 4 + ks] =
                    *reinterpret_cast<const short8*>(mp + j * 2048 + ks * 32);
    };

    // ---- issue M(t=0) loads first (deepest in flight)
    loadM(0, Mb0);

    // ---- stage X: lanes = (v-pair, l-half) -> 32 lines/instr @32B used.
    // LDS row (n*16+c)*256B, col byte = 4*p ^ ((c&7)<<4)   (p = v/2)
    {
        const int half = tid & 1;
        const int p5 = (tid >> 1) & 31;
        #pragma unroll
        for (int i = 0; i < 8; ++i) {
            const int g = i * 4 + wid;       // 0..31
            const int c = g >> 1, pg = g & 1;
            const int p = pg * 32 + p5;      // v-pair 0..63
            const int v = p * 2;
            const float* p0 = x + (size_t)b * 1048576 + c * 65536 + d * 16384 +
                              v * 128 + l0 + half * 4;
            const float4 q0 = *reinterpret_cast<const float4*>(p0);        // v
            const float4 q1 = *reinterpret_cast<const float4*>(p0 + 128);  // v+1
            const float a0[4] = {q0.x, q0.y, q0.z, q0.w};
            const float a1[4] = {q1.x, q1.y, q1.z, q1.w};
            const int colb = (4 * p) ^ ((c & 7) << 4);
            #pragma unroll
            for (int j = 0; j < 4; ++j) {
                const int n = half * 4 + j;
                *reinterpret_cast<unsigned*>(lds + (n * 16 + c) * 256 + colb) =
                    pack2(a0[j], a1[j]);
            }
        }
    }

    // ---- W fragments (A-operand of phase B), zero-padded 8th t-slot
    short8 Wf[4];
    #pragma unroll
    for (int p = 0; p < 4; ++p) {
        short8 w;
        #pragma unroll
        for (int j = 0; j < 8; ++j) {
            const int tc = lg * 8 + j, t = 2 * p + (tc >> 4), c = tc & 15;
            const float wv = (t < 7) ? mlpW[d * 1792 + lr * 112 + t * 16 + c] : 0.f;
            w[j] = (short)f2bf(wv);
        }
        Wf[p] = w;
    }

    __syncthreads();   // X staged

    // ---- X A-fragments -> registers (X LDS dead after; Z overlays)
    short8 Xf[4][4];
    {
        const int swz = (lr & 7) << 4;
        #pragma unroll
        for (int rti = 0; rti < 4; ++rti) {
            const int base = ((wr * 4 + rti) * 16 + lr) * 256;
            #pragma unroll
            for (int ks = 0; ks < 4; ++ks)
                Xf[rti][ks] = *reinterpret_cast<const short8*>(
                    lds + base + ((ks * 64 + lg * 16) ^ swz));
        }
    }
    __syncthreads();   // all waves done reading X before Z overlay writes

    f32x4 Y[2][4];
    #pragma unroll
    for (int ni = 0; ni < 2; ++ni)
        #pragma unroll
        for (int kt = 0; kt < 4; ++kt) Y[ni][kt] = zero4;

    // phase A + Z-write for one t; tp/zeroTail are literal at each callsite
    auto phaseA_Z = [&](const short8 (&cur)[8], int tp, bool zeroTail) {
        f32x4 D[4][2];
        #pragma unroll
        for (int rti = 0; rti < 4; ++rti) { D[rti][0] = zero4; D[rti][1] = zero4; }
        #pragma unroll
        for (int ks = 0; ks < 4; ++ks) {
            #pragma unroll
            for (int rti = 0; rti < 4; ++rti) {
                D[rti][0] = __builtin_amdgcn_mfma_f32_16x16x32_bf16(
                    Xf[rti][ks], cur[ks], D[rti][0], 0, 0, 0);
                D[rti][1] = __builtin_amdgcn_mfma_f32_16x16x32_bf16(
                    Xf[rti][ks], cur[4 + ks], D[rti][1], 0, 0, 0);
            }
        }
        #pragma unroll
        for (int rti = 0; rti < 4; ++rti) {
            #pragma unroll
            for (int j = 0; j < 2; ++j) {
                const int n = wr * 4 + rti;
                const int kp = (wk * 2 + j) * 16 + lr;
                uint2 zz;
                zz.x = pack2(D[rti][j][0], D[rti][j][1]);
                zz.y = pack2(D[rti][j][2], D[rti][j][3]);
                *reinterpret_cast<uint2*>(
                    lds + n * 4096 + ((kp * 64 + tp * 32 + lg * 8) ^ ((kp & 7) << 4))) = zz;
                if (zeroTail) {
                    const uint2 z0 = {0u, 0u};
                    *reinterpret_cast<uint2*>(
                        lds + n * 4096 + ((kp * 64 + 32 + lg * 8) ^ ((kp & 7) << 4))) = z0;
                }
            }
        }
    };

    auto phaseB = [&](const short8& Wfp) {
        #pragma unroll
        for (int ni = 0; ni < 2; ++ni) {
            const int n = wid * 2 + ni;
            #pragma unroll
            for (int ktl = 0; ktl < 4; ++ktl) {
                const int kp = ktl * 16 + lr;
                const short8 Bfz = *reinterpret_cast<const short8*>(
                    lds + n * 4096 + ((kp * 64 + lg * 16) ^ ((kp & 7) << 4)));
                Y[ni][ktl] = __builtin_amdgcn_mfma_f32_16x16x32_bf16(
                    Wfp, Bfz, Y[ni][ktl], 0, 0, 0);
            }
        }
    };

    // ---- hand-unrolled t-sequence with named double buffers (no runtime indexing)
    loadM(1, Mb1);              phaseA_Z(Mb0, 0, false);   // t0 (I)
    loadM(2, Mb0);              phaseA_Z(Mb1, 1, false);   // t1 (A0)
    __syncthreads();  phaseB(Wf[0]);  __syncthreads();
    loadM(3, Mb1);              phaseA_Z(Mb0, 0, false);   // t2 (A0²)
    loadM(4, Mb0);              phaseA_Z(Mb1, 1, false);   // t3 (A1)
    __syncthreads();  phaseB(Wf[1]);  __syncthreads();
    loadM(5 + 2 * d, Mb1);      phaseA_Z(Mb0, 0, false);   // t4 (A1²)
    loadM(6 + 2 * d, Mb0);      phaseA_Z(Mb1, 1, false);   // t5 (P_d)
    __syncthreads();  phaseB(Wf[2]);  __syncthreads();
                                phaseA_Z(Mb0, 0, true);    // t6 (P²_d) + zero tp=1
    __syncthreads();  phaseB(Wf[3]);  __syncthreads();

    // ---- Y bounce: regs -> LDS [o][k64][l8] f32 (byte ^= (k&12))
    #pragma unroll
    for (int ni = 0; ni < 2; ++ni) {
        const int l = wid * 2 + ni;
        #pragma unroll
        for (int ktl = 0; ktl < 4; ++ktl) {
            const int k = ktl * 16 + lr;
            #pragma unroll
            for (int r = 0; r < 4; ++r) {
                const int o = lg * 4 + r;
                *reinterpret_cast<float*>(
                    lds + o * 2048 + k * 32 + ((l * 4) ^ (k & 12))) = Y[ni][ktl][r];
            }
        }
    }
    __syncthreads();   // Y chunk complete

    // ---- coalesced dwordx4 stores, lanes spanning (k, l-half): 32 lines @32B
    {
        const int half = tid & 1;
        const int klo = (tid >> 1) & 31;
        #pragma unroll
        for (int i = 0; i < 8; ++i) {
            const int g = i * 4 + wid;        // 0..31
            const int o = g >> 1, kg = g & 1;
            const int k = kg * 32 + klo;      // 0..63 local
            const int pp = (k >> 2) & 3;
            const float4 F = *reinterpret_cast<const float4*>(
                lds + o * 2048 + k * 32 + half * 16);
            float4 s1, s2;
            if (pp & 1) { s1.x = F.y; s1.y = F.x; s1.z = F.w; s1.w = F.z; }
            else        { s1 = F; }
            if (pp & 2) { s2.x = s1.z; s2.y = s1.w; s2.z = s1.x; s2.w = s1.y; }
            else        { s2 = s1; }
            const float bv = mlpB[d * 16 + o];
            s2.x += bv; s2.y += bv; s2.z += bv; s2.w += bv;
            float* gp = out + (size_t)b * 1048576 + o * 65536 + d * 16384 +
                        (kh * 64 + k) * 128 + l0 + half * 4;
            *reinterpret_cast<float4*>(gp) = s2;
        }
    }
}

}  // namespace

extern "C" void kernel_launch(void* const* d_in, const int* in_sizes, int n_in,
                              void* d_out, int out_size, void* d_ws, size_t ws_size,
                              hipStream_t stream)
{
    const float* x    = (const float*)d_in[0];
    const float* sup  = (const float*)d_in[1];
    const float* nv1  = (const float*)d_in[2];
    const float* nv2  = (const float*)d_in[3];
    const float* impW = (const float*)d_in[4];
    const float* impB = (const float*)d_in[5];
    const float* mlpW = (const float*)d_in[6];
    const float* mlpB = (const float*)d_in[7];
    float* outp = (float*)d_out;

    float* fm = (float*)d_ws;                                        // fp32 mats
    unsigned short* wbm = (unsigned short*)((char*)d_ws + 786432);   // 13 × 32KB bf16

    build_adj<<<6, 256, 0, stream>>>(sup, nv1, nv2, impW, impB, fm);
    square_cvt<<<103, 256, 0, stream>>>(fm, wbm);
    fused_mfma<<<2048, 256, 0, stream>>>(x, wbm, mlpW, mlpB, outp);
}